// Round 3
// baseline (81.948 us; speedup 1.0000x reference)
//
#include <hip/hip_runtime.h>
#include <math.h>

#define NPTS 4096
#define NB 16
#define THREADS 256
#define RADIUSF 0.07f
#define HF 0.03f
#define EPSF 1e-12f
#define Q 4                       // queries per thread (register-blocked)

// Insert d into sorted-ascending 6-list: b0'=min(b0,d), bk'=med3(d,b(k-1),bk).
// 6 independent VALU ops (v_min + 5x v_med3), no dependency chain.
#define INS6(L, dd) do {                                          \
    const float _d  = (dd);                                       \
    const float _n0 = fminf((L)[0], _d);                          \
    const float _n1 = __builtin_amdgcn_fmed3f(_d, (L)[0], (L)[1]);\
    const float _n2 = __builtin_amdgcn_fmed3f(_d, (L)[1], (L)[2]);\
    const float _n3 = __builtin_amdgcn_fmed3f(_d, (L)[2], (L)[3]);\
    const float _n4 = __builtin_amdgcn_fmed3f(_d, (L)[3], (L)[4]);\
    const float _n5 = __builtin_amdgcn_fmed3f(_d, (L)[4], (L)[5]);\
    (L)[0]=_n0; (L)[1]=_n1; (L)[2]=_n2; (L)[3]=_n3; (L)[4]=_n4; (L)[5]=_n5; \
} while (0)

// ---------------------------------------------------------------------------
// Pass 1: per (batch, query-chunk, cand-split) block. Each thread owns Q=4
// queries (stride-256 apart); scans NCAND candidates staged SoA in LDS and
// keeps the 6 smallest squared distances per query (self included, == 0).
// One broadcast candidate read feeds 4 queries -> LDS traffic / 4.
// ---------------------------------------------------------------------------
template<int NCAND>
__global__ __launch_bounds__(THREADS, 2) void knn_split_kernel(
    const float* __restrict__ pred, float* __restrict__ cand6)
{
    constexpr int S  = NPTS / NCAND;             // candidate splits
    constexpr int QC = NPTS / (THREADS * Q);     // query chunks per batch (4)

    __shared__ __align__(16) float sx[NCAND];
    __shared__ __align__(16) float sy[NCAND];
    __shared__ __align__(16) float sz[NCAND];

    const int bid = blockIdx.x;
    const int cs  = bid % S;                     // candidate split
    const int qc  = (bid / S) % QC;              // query chunk
    const int b   = bid / (S * QC);              // batch

    const float* pb  = pred + (size_t)b * NPTS * 3;
    const float* src = pb + (size_t)cs * NCAND * 3;

    // Stage AoS -> SoA into LDS.
    for (int p = threadIdx.x; p < NCAND; p += THREADS) {
        sx[p] = src[3 * p + 0];
        sy[p] = src[3 * p + 1];
        sz[p] = src[3 * p + 2];
    }
    __syncthreads();

    // Q query coords per thread, stride-256 within a 1024-query chunk.
    float qx[Q], qy[Q], qz[Q];
    int   qn[Q];
    #pragma unroll
    for (int j = 0; j < Q; ++j) {
        qn[j] = qc * (THREADS * Q) + j * THREADS + threadIdx.x;
        qx[j] = pb[3 * qn[j] + 0];
        qy[j] = pb[3 * qn[j] + 1];
        qz[j] = pb[3 * qn[j] + 2];
    }

    float L[Q][6];
    #pragma unroll
    for (int j = 0; j < Q; ++j)
        #pragma unroll
        for (int i = 0; i < 6; ++i) L[j][i] = 1e30f;

    const float4* X4 = (const float4*)sx;
    const float4* Y4 = (const float4*)sy;
    const float4* Z4 = (const float4*)sz;

    #pragma unroll 2
    for (int g = 0; g < NCAND / 4; ++g) {
        const float4 X = X4[g];                  // 3 broadcast ds_read_b128
        const float4 Y = Y4[g];
        const float4 Z = Z4[g];

        #pragma unroll
        for (int j = 0; j < Q; ++j) {
            const float dx0 = X.x - qx[j], dy0 = Y.x - qy[j], dz0 = Z.x - qz[j];
            const float dx1 = X.y - qx[j], dy1 = Y.y - qy[j], dz1 = Z.y - qz[j];
            const float dx2 = X.z - qx[j], dy2 = Y.z - qy[j], dz2 = Z.z - qz[j];
            const float dx3 = X.w - qx[j], dy3 = Y.w - qy[j], dz3 = Z.w - qz[j];
            const float d0 = fmaf(dz0, dz0, fmaf(dy0, dy0, dx0 * dx0));
            const float d1 = fmaf(dz1, dz1, fmaf(dy1, dy1, dx1 * dx1));
            const float d2 = fmaf(dz2, dz2, fmaf(dy2, dy2, dx2 * dx2));
            const float d3 = fmaf(dz3, dz3, fmaf(dy3, dy3, dx3 * dx3));
            INS6(L[j], d0);
            INS6(L[j], d1);
            INS6(L[j], d2);
            INS6(L[j], d3);
        }
    }

    // Layout: cand6[((b*S+cs)*6 + i)*NPTS + n]  (coalesced stores & loads)
    #pragma unroll
    for (int j = 0; j < Q; ++j) {
        float* o = cand6 + ((size_t)(b * S + cs) * 6) * NPTS + qn[j];
        #pragma unroll
        for (int i = 0; i < 6; ++i) o[i * NPTS] = L[j][i];
    }
}

// ---------------------------------------------------------------------------
// Pass 2: merge the S per-split 6-lists per query, drop self (exact 0),
// evaluate loss on the 5 NN, block-reduce to partial sums (deterministic).
// ---------------------------------------------------------------------------
template<int S>
__global__ __launch_bounds__(THREADS) void merge_loss_kernel(
    const float* __restrict__ cand6, float* __restrict__ partial)
{
    __shared__ float red[THREADS / 64];
    const int q = blockIdx.x * THREADS + threadIdx.x;   // global query id
    const int b = q >> 12;                              // /4096
    const int n = q & (NPTS - 1);

    float L[6];
    #pragma unroll
    for (int i = 0; i < 6; ++i) L[i] = 1e30f;

    #pragma unroll
    for (int cs = 0; cs < S; ++cs) {
        const float* p = cand6 + ((size_t)(b * S + cs) * 6) * NPTS + n;
        #pragma unroll
        for (int i = 0; i < 6; ++i) INS6(L, p[i * NPTS]);
    }

    // L[0] == self (exactly 0): drop. Neighbors are L[1..5].
    float loss = 0.0f;
    #pragma unroll
    for (int i = 1; i < 6; ++i) {
        const float d = sqrtf(fmaxf(L[i], EPSF));
        const float t = d / HF;
        loss += (RADIUSF - d) * expf(-t * t);
    }

    #pragma unroll
    for (int off = 32; off > 0; off >>= 1)
        loss += __shfl_down(loss, off, 64);

    const int wave = threadIdx.x >> 6;
    const int lane = threadIdx.x & 63;
    if (lane == 0) red[wave] = loss;
    __syncthreads();
    if (threadIdx.x == 0) {
        float s = 0.0f;
        #pragma unroll
        for (int w = 0; w < THREADS / 64; ++w) s += red[w];
        partial[blockIdx.x] = s;   // block = 256 consecutive queries
    }
}

__global__ void final_reduce_kernel(const float* __restrict__ partial,
                                    float* __restrict__ out)
{
    const int b = threadIdx.x;
    if (b < NB) {
        float s = 0.0f;
        #pragma unroll
        for (int i = 0; i < 16; ++i) s += partial[b * 16 + i];
        out[b] = s * (1.0f / ((float)NPTS * 5.0f));
    }
}

// ---------------------------------------------------------------------------
// Emergency path (tiny workspace): monolithic, loss computed in-kernel.
// ---------------------------------------------------------------------------
__global__ __launch_bounds__(THREADS) void mono_kernel(
    const float* __restrict__ pred, float* __restrict__ partial)
{
    __shared__ __align__(16) float sx[NPTS];
    __shared__ __align__(16) float sy[NPTS];
    __shared__ __align__(16) float sz[NPTS];
    __shared__ float red[THREADS / 64];

    const int b     = blockIdx.x >> 4;
    const int chunk = blockIdx.x & 15;
    const float* pb = pred + (size_t)b * NPTS * 3;

    for (int p = threadIdx.x; p < NPTS; p += THREADS) {
        sx[p] = pb[3 * p + 0]; sy[p] = pb[3 * p + 1]; sz[p] = pb[3 * p + 2];
    }
    __syncthreads();

    const int n = chunk * THREADS + threadIdx.x;
    const float qx = pb[3 * n], qy = pb[3 * n + 1], qz = pb[3 * n + 2];

    float A[6], B[6];
    #pragma unroll
    for (int i = 0; i < 6; ++i) { A[i] = 1e30f; B[i] = 1e30f; }

    const float4* X4 = (const float4*)sx;
    const float4* Y4 = (const float4*)sy;
    const float4* Z4 = (const float4*)sz;

    #pragma unroll 2
    for (int g = 0; g < NPTS / 4; ++g) {
        const float4 X = X4[g], Y = Y4[g], Z = Z4[g];
        const float dx0 = X.x - qx, dy0 = Y.x - qy, dz0 = Z.x - qz;
        const float dx1 = X.y - qx, dy1 = Y.y - qy, dz1 = Z.y - qz;
        const float dx2 = X.z - qx, dy2 = Y.z - qy, dz2 = Z.z - qz;
        const float dx3 = X.w - qx, dy3 = Y.w - qy, dz3 = Z.w - qz;
        const float d0 = fmaf(dz0, dz0, fmaf(dy0, dy0, dx0 * dx0));
        const float d1 = fmaf(dz1, dz1, fmaf(dy1, dy1, dx1 * dx1));
        const float d2 = fmaf(dz2, dz2, fmaf(dy2, dy2, dx2 * dx2));
        const float d3 = fmaf(dz3, dz3, fmaf(dy3, dy3, dx3 * dx3));
        INS6(A, d0);
        INS6(B, d1);
        INS6(A, d2);
        INS6(B, d3);
    }
    #pragma unroll
    for (int i = 0; i < 6; ++i) INS6(A, B[i]);

    float loss = 0.0f;
    #pragma unroll
    for (int i = 1; i < 6; ++i) {
        const float d = sqrtf(fmaxf(A[i], EPSF));
        const float t = d / HF;
        loss += (RADIUSF - d) * expf(-t * t);
    }
    #pragma unroll
    for (int off = 32; off > 0; off >>= 1)
        loss += __shfl_down(loss, off, 64);
    const int wave = threadIdx.x >> 6;
    const int lane = threadIdx.x & 63;
    if (lane == 0) red[wave] = loss;
    __syncthreads();
    if (threadIdx.x == 0) {
        float s = 0.0f;
        #pragma unroll
        for (int w = 0; w < THREADS / 64; ++w) s += red[w];
        partial[blockIdx.x] = s;
    }
}

extern "C" void kernel_launch(void* const* d_in, const int* in_sizes, int n_in,
                              void* d_out, int out_size, void* d_ws, size_t ws_size,
                              hipStream_t stream)
{
    const float* pred = (const float*)d_in[0];
    float* out        = (float*)d_out;

    const size_t f6 = (size_t)NB * 6 * NPTS;     // floats per S=1 list set
    constexpr int QC = NPTS / (THREADS * Q);     // 4 query chunks per batch

    if (ws_size >= (f6 * 8 + 256) * sizeof(float)) {
        // Primary: S=8 splits, Q=4 queries/thread -> 512 blocks (2/CU).
        float* cand6   = (float*)d_ws;
        float* partial = cand6 + f6 * 8;
        knn_split_kernel<NPTS / 8><<<dim3(NB * QC * 8), dim3(THREADS), 0, stream>>>(pred, cand6);
        merge_loss_kernel<8><<<dim3(256), dim3(THREADS), 0, stream>>>(cand6, partial);
        final_reduce_kernel<<<dim3(1), dim3(64), 0, stream>>>(partial, out);
    } else if (ws_size >= (f6 * 4 + 256) * sizeof(float)) {
        float* cand6   = (float*)d_ws;
        float* partial = cand6 + f6 * 4;
        knn_split_kernel<NPTS / 4><<<dim3(NB * QC * 4), dim3(THREADS), 0, stream>>>(pred, cand6);
        merge_loss_kernel<4><<<dim3(256), dim3(THREADS), 0, stream>>>(cand6, partial);
        final_reduce_kernel<<<dim3(1), dim3(64), 0, stream>>>(partial, out);
    } else {
        float* partial = (float*)d_ws;            // 256 floats
        mono_kernel<<<dim3(256), dim3(THREADS), 0, stream>>>(pred, partial);
        final_reduce_kernel<<<dim3(1), dim3(64), 0, stream>>>(partial, out);
    }
}

// Round 4
// 78.212 us; speedup vs baseline: 1.0478x; 1.0478x over previous
//
#include <hip/hip_runtime.h>
#include <math.h>

#define NPTS 4096
#define NB 16
#define THREADS 256
#define RADIUSF 0.07f
#define HF 0.03f
#define EPSF 1e-12f

#define GRIDD 8
#define NCELL (GRIDD * GRIDD * GRIDD)   // 512
#define COV2 0.015625f                  // (1/8)^2 coverage radius squared

// Insert d into sorted-ascending 6-list: L0'=min(L0,d), Lk'=med3(d,L(k-1),Lk).
#define INS6(L, dd) do {                                          \
    const float _d  = (dd);                                       \
    const float _n0 = fminf((L)[0], _d);                          \
    const float _n1 = __builtin_amdgcn_fmed3f(_d, (L)[0], (L)[1]);\
    const float _n2 = __builtin_amdgcn_fmed3f(_d, (L)[1], (L)[2]);\
    const float _n3 = __builtin_amdgcn_fmed3f(_d, (L)[2], (L)[3]);\
    const float _n4 = __builtin_amdgcn_fmed3f(_d, (L)[3], (L)[4]);\
    const float _n5 = __builtin_amdgcn_fmed3f(_d, (L)[4], (L)[5]);\
    (L)[0]=_n0; (L)[1]=_n1; (L)[2]=_n2; (L)[3]=_n3; (L)[4]=_n4; (L)[5]=_n5; \
} while (0)

__device__ __forceinline__ float loss5(const float* L) {
    float loss = 0.0f;
    #pragma unroll
    for (int i = 1; i < 6; ++i) {               // L[0] == self (exact 0)
        const float d = sqrtf(fmaxf(L[i], EPSF));
        const float t = d / HF;
        loss += (RADIUSF - d) * expf(-t * t);
    }
    return loss;
}

// ---------------------------------------------------------------------------
// Kernel A: per batch, bin points into 8^3 cells (counting sort).
// Output: sortedP[b][4096] float4 (x,y,z,0) cell-sorted; cellStart[b][513].
// ---------------------------------------------------------------------------
__global__ __launch_bounds__(512) void bin_kernel(
    const float* __restrict__ pred, float4* __restrict__ sortedP,
    int* __restrict__ cellStart)
{
    __shared__ int h[NCELL];
    __shared__ int s[NCELL];
    __shared__ int cur[NCELL];
    __shared__ int start[NCELL + 1];

    const int b = blockIdx.x, t = threadIdx.x;
    h[t] = 0; cur[t] = 0;
    __syncthreads();

    const float* pb = pred + (size_t)b * NPTS * 3;
    int cid[8];
    #pragma unroll
    for (int k = 0; k < 8; ++k) {
        const int p = k * 512 + t;
        const float x = pb[3 * p], y = pb[3 * p + 1], z = pb[3 * p + 2];
        const int ix = min(GRIDD - 1, max(0, (int)(x * (float)GRIDD)));
        const int iy = min(GRIDD - 1, max(0, (int)(y * (float)GRIDD)));
        const int iz = min(GRIDD - 1, max(0, (int)(z * (float)GRIDD)));
        cid[k] = (ix << 6) | (iy << 3) | iz;
        atomicAdd(&h[cid[k]], 1);
    }
    __syncthreads();

    // Hillis-Steele inclusive scan of h into s (512 entries, 512 threads).
    int val = h[t];
    s[t] = val;
    __syncthreads();
    for (int off = 1; off < NCELL; off <<= 1) {
        const int u = (t >= off) ? s[t - off] : 0;
        __syncthreads();
        val += u; s[t] = val;
        __syncthreads();
    }
    start[t] = val - h[t];                       // exclusive start
    if (t == 0) start[NCELL] = NPTS;
    __syncthreads();

    #pragma unroll
    for (int k = 0; k < 8; ++k) {
        const int p = k * 512 + t;
        const float x = pb[3 * p], y = pb[3 * p + 1], z = pb[3 * p + 2];
        const int dst = start[cid[k]] + atomicAdd(&cur[cid[k]], 1);
        sortedP[(size_t)b * NPTS + dst] = make_float4(x, y, z, 0.0f);
    }

    cellStart[b * (NCELL + 1) + t] = start[t];
    if (t == 0) cellStart[b * (NCELL + 1) + NCELL] = NPTS;
}

// ---------------------------------------------------------------------------
// Kernel B: grid kNN search. Thread = one sorted query. Scan 3x3x3 cells as
// 9 contiguous z-ranges. Exact iff L[5] <= COV2 (coverage radius = cell h);
// otherwise flag for brute-force fallback.
// ---------------------------------------------------------------------------
__global__ __launch_bounds__(THREADS) void search_kernel(
    const float4* __restrict__ sortedP, const int* __restrict__ cellStart,
    float* __restrict__ partial, int* __restrict__ fcount,
    int* __restrict__ flist)
{
    __shared__ int cs[NCELL + 1];
    __shared__ float red[THREADS / 64];

    const int q = blockIdx.x * THREADS + threadIdx.x;   // global sorted query
    const int b = q >> 12;

    const int* cbase = cellStart + b * (NCELL + 1);
    for (int i = threadIdx.x; i < NCELL + 1; i += THREADS) cs[i] = cbase[i];
    __syncthreads();

    const float4 me = sortedP[q];
    const int ix = min(GRIDD - 1, max(0, (int)(me.x * (float)GRIDD)));
    const int iy = min(GRIDD - 1, max(0, (int)(me.y * (float)GRIDD)));
    const int iz = min(GRIDD - 1, max(0, (int)(me.z * (float)GRIDD)));

    float L[6];
    #pragma unroll
    for (int i = 0; i < 6; ++i) L[i] = 1e30f;

    const float4* sp = sortedP + (size_t)b * NPTS;
    const int z0 = max(iz - 1, 0), z1 = min(iz + 1, GRIDD - 1);

    #pragma unroll
    for (int dx = -1; dx <= 1; ++dx) {
        const int X = ix + dx;
        if ((unsigned)X > (unsigned)(GRIDD - 1)) continue;
        #pragma unroll
        for (int dy = -1; dy <= 1; ++dy) {
            const int Y = iy + dy;
            if ((unsigned)Y > (unsigned)(GRIDD - 1)) continue;
            const int row = (X << 6) | (Y << 3);
            int p        = cs[row + z0];
            const int pe = cs[row + z1 + 1];
            for (; p < pe; ++p) {
                const float4 c = sp[p];
                const float ddx = c.x - me.x;
                const float ddy = c.y - me.y;
                const float ddz = c.z - me.z;
                const float d = fmaf(ddz, ddz, fmaf(ddy, ddy, ddx * ddx));
                INS6(L, d);
            }
        }
    }

    float loss = 0.0f;
    if (L[5] <= COV2) {
        loss = loss5(L);
    } else {
        const int slot = atomicAdd(fcount, 1);
        flist[slot] = q;
    }

    #pragma unroll
    for (int off = 32; off > 0; off >>= 1)
        loss += __shfl_down(loss, off, 64);
    const int wave = threadIdx.x >> 6, lane = threadIdx.x & 63;
    if (lane == 0) red[wave] = loss;
    __syncthreads();
    if (threadIdx.x == 0) {
        float ssum = 0.0f;
        #pragma unroll
        for (int w = 0; w < THREADS / 64; ++w) ssum += red[w];
        partial[blockIdx.x] = ssum;
    }
}

// ---------------------------------------------------------------------------
// Kernel C: exact brute-force fallback, one wave per flagged query.
// Tree merge via shfl_down (each lane's list merged exactly once -> exact).
// ---------------------------------------------------------------------------
#define FB_BLOCKS 64
#define FB_WAVES (FB_BLOCKS * THREADS / 64)   // 256

__global__ __launch_bounds__(THREADS) void fallback_kernel(
    const float4* __restrict__ sortedP, const int* __restrict__ fcount,
    const int* __restrict__ flist, float* __restrict__ extra)
{
    const int wid  = (blockIdx.x * THREADS + threadIdx.x) >> 6;
    const int lane = threadIdx.x & 63;
    const int nf = *fcount;

    for (int i = wid; i < nf; i += FB_WAVES) {
        const int q = flist[i];
        const int b = q >> 12;
        const float4* sp = sortedP + (size_t)b * NPTS;
        const float4 me = sortedP[q];

        float L[6];
        #pragma unroll
        for (int j = 0; j < 6; ++j) L[j] = 1e30f;

        for (int p = lane; p < NPTS; p += 64) {
            const float4 c = sp[p];
            const float ddx = c.x - me.x;
            const float ddy = c.y - me.y;
            const float ddz = c.z - me.z;
            const float d = fmaf(ddz, ddz, fmaf(ddy, ddy, ddx * ddx));
            INS6(L, d);
        }
        // shfl_down tree: lane 0 merges every lane exactly once.
        #pragma unroll
        for (int off = 32; off >= 1; off >>= 1) {
            float R[6];
            #pragma unroll
            for (int j = 0; j < 6; ++j) R[j] = __shfl_down(L[j], off, 64);
            #pragma unroll
            for (int j = 0; j < 6; ++j) INS6(L, R[j]);
        }
        if (lane == 0) atomicAdd(&extra[b], loss5(L));
    }
}

__global__ void final_kernel(const float* __restrict__ partial,
                             const float* __restrict__ extra,
                             float* __restrict__ out)
{
    const int b = threadIdx.x;
    if (b < NB) {
        float s = extra[b];
        #pragma unroll
        for (int i = 0; i < 16; ++i) s += partial[b * 16 + i];
        out[b] = s * (1.0f / ((float)NPTS * 5.0f));
    }
}

// ---------------------------------------------------------------------------
// Emergency path (tiny workspace): monolithic brute force (round-3 code).
// ---------------------------------------------------------------------------
__global__ __launch_bounds__(THREADS) void mono_kernel(
    const float* __restrict__ pred, float* __restrict__ partial)
{
    __shared__ __align__(16) float sx[NPTS];
    __shared__ __align__(16) float sy[NPTS];
    __shared__ __align__(16) float sz[NPTS];
    __shared__ float red[THREADS / 64];

    const int b     = blockIdx.x >> 4;
    const int chunk = blockIdx.x & 15;
    const float* pb = pred + (size_t)b * NPTS * 3;

    for (int p = threadIdx.x; p < NPTS; p += THREADS) {
        sx[p] = pb[3 * p + 0]; sy[p] = pb[3 * p + 1]; sz[p] = pb[3 * p + 2];
    }
    __syncthreads();

    const int n = chunk * THREADS + threadIdx.x;
    const float qx = pb[3 * n], qy = pb[3 * n + 1], qz = pb[3 * n + 2];

    float A[6], B[6];
    #pragma unroll
    for (int i = 0; i < 6; ++i) { A[i] = 1e30f; B[i] = 1e30f; }

    const float4* X4 = (const float4*)sx;
    const float4* Y4 = (const float4*)sy;
    const float4* Z4 = (const float4*)sz;

    #pragma unroll 2
    for (int g = 0; g < NPTS / 4; ++g) {
        const float4 X = X4[g], Y = Y4[g], Z = Z4[g];
        const float dx0 = X.x - qx, dy0 = Y.x - qy, dz0 = Z.x - qz;
        const float dx1 = X.y - qx, dy1 = Y.y - qy, dz1 = Z.y - qz;
        const float dx2 = X.z - qx, dy2 = Y.z - qy, dz2 = Z.z - qz;
        const float dx3 = X.w - qx, dy3 = Y.w - qy, dz3 = Z.w - qz;
        const float d0 = fmaf(dz0, dz0, fmaf(dy0, dy0, dx0 * dx0));
        const float d1 = fmaf(dz1, dz1, fmaf(dy1, dy1, dx1 * dx1));
        const float d2 = fmaf(dz2, dz2, fmaf(dy2, dy2, dx2 * dx2));
        const float d3 = fmaf(dz3, dz3, fmaf(dy3, dy3, dx3 * dx3));
        INS6(A, d0);
        INS6(B, d1);
        INS6(A, d2);
        INS6(B, d3);
    }
    #pragma unroll
    for (int i = 0; i < 6; ++i) INS6(A, B[i]);

    float loss = loss5(A);
    #pragma unroll
    for (int off = 32; off > 0; off >>= 1)
        loss += __shfl_down(loss, off, 64);
    const int wave = threadIdx.x >> 6, lane = threadIdx.x & 63;
    if (lane == 0) red[wave] = loss;
    __syncthreads();
    if (threadIdx.x == 0) {
        float s = 0.0f;
        #pragma unroll
        for (int w = 0; w < THREADS / 64; ++w) s += red[w];
        partial[blockIdx.x] = s;
    }
}

__global__ void mono_final_kernel(const float* __restrict__ partial,
                                  float* __restrict__ out)
{
    const int b = threadIdx.x;
    if (b < NB) {
        float s = 0.0f;
        #pragma unroll
        for (int i = 0; i < 16; ++i) s += partial[b * 16 + i];
        out[b] = s * (1.0f / ((float)NPTS * 5.0f));
    }
}

extern "C" void kernel_launch(void* const* d_in, const int* in_sizes, int n_in,
                              void* d_out, int out_size, void* d_ws, size_t ws_size,
                              hipStream_t stream)
{
    const float* pred = (const float*)d_in[0];
    float* out        = (float*)d_out;
    char* ws          = (char*)d_ws;

    // Workspace layout (bytes):
    const size_t off_sorted = 0;                               // 16*4096*16 = 1048576
    const size_t off_cs     = off_sorted + (size_t)NB * NPTS * sizeof(float4);
    const size_t off_zero   = (off_cs + (size_t)NB * (NCELL + 1) * sizeof(int) + 127) & ~(size_t)127;
    const size_t off_fcount = off_zero;                        // int
    const size_t off_extra  = off_zero + 16;                   // 16 floats
    const size_t off_part   = off_zero + 128;                  // 256 floats
    const size_t off_flist  = off_part + 256 * sizeof(float);  // 65536 ints
    const size_t need       = off_flist + (size_t)NB * NPTS * sizeof(int);

    if (ws_size >= need) {
        float4* sortedP = (float4*)(ws + off_sorted);
        int*    cellS   = (int*)(ws + off_cs);
        int*    fcount  = (int*)(ws + off_fcount);
        float*  extra   = (float*)(ws + off_extra);
        float*  partial = (float*)(ws + off_part);
        int*    flist   = (int*)(ws + off_flist);

        hipMemsetAsync(ws + off_zero, 0, 128, stream);  // fcount + extra
        bin_kernel<<<dim3(NB), dim3(512), 0, stream>>>(pred, sortedP, cellS);
        search_kernel<<<dim3(NB * NPTS / THREADS), dim3(THREADS), 0, stream>>>(
            sortedP, cellS, partial, fcount, flist);
        fallback_kernel<<<dim3(FB_BLOCKS), dim3(THREADS), 0, stream>>>(
            sortedP, fcount, flist, extra);
        final_kernel<<<dim3(1), dim3(64), 0, stream>>>(partial, extra, out);
    } else {
        float* partial = (float*)d_ws;                 // 256 floats
        mono_kernel<<<dim3(256), dim3(THREADS), 0, stream>>>(pred, partial);
        mono_final_kernel<<<dim3(1), dim3(64), 0, stream>>>(partial, out);
    }
}

// Round 5
// 58.764 us; speedup vs baseline: 1.3945x; 1.3309x over previous
//
#include <hip/hip_runtime.h>
#include <math.h>

#define NPTS 4096
#define NB 16
#define THREADS 256
#define RADIUSF 0.07f
#define HF 0.03f
#define EPSF 1e-12f

#define GRIDD 8
#define NCELL (GRIDD * GRIDD * GRIDD)   // 512
#define COV2 0.015625f                  // (1/8)^2 coverage radius squared

// Insert d into sorted-ascending 6-list: L0'=min(L0,d), Lk'=med3(d,L(k-1),Lk).
#define INS6(L, dd) do {                                          \
    const float _d  = (dd);                                       \
    const float _n0 = fminf((L)[0], _d);                          \
    const float _n1 = __builtin_amdgcn_fmed3f(_d, (L)[0], (L)[1]);\
    const float _n2 = __builtin_amdgcn_fmed3f(_d, (L)[1], (L)[2]);\
    const float _n3 = __builtin_amdgcn_fmed3f(_d, (L)[2], (L)[3]);\
    const float _n4 = __builtin_amdgcn_fmed3f(_d, (L)[3], (L)[4]);\
    const float _n5 = __builtin_amdgcn_fmed3f(_d, (L)[4], (L)[5]);\
    (L)[0]=_n0; (L)[1]=_n1; (L)[2]=_n2; (L)[3]=_n3; (L)[4]=_n4; (L)[5]=_n5; \
} while (0)

__device__ __forceinline__ float loss5(const float* L) {
    float loss = 0.0f;
    #pragma unroll
    for (int i = 1; i < 6; ++i) {               // L[0] == self (exact 0)
        const float d = sqrtf(fmaxf(L[i], EPSF));
        const float t = d / HF;
        loss += (RADIUSF - d) * expf(-t * t);
    }
    return loss;
}

// ---------------------------------------------------------------------------
// Kernel A: per batch, bin points into 8^3 cells (counting sort).
// Wave-shfl scan (2 syncthreads) instead of Hillis-Steele (9).
// ---------------------------------------------------------------------------
__global__ __launch_bounds__(512) void bin_kernel(
    const float* __restrict__ pred, float4* __restrict__ sortedP,
    int* __restrict__ cellStart)
{
    __shared__ int h[NCELL];
    __shared__ int cur[NCELL];
    __shared__ int start[NCELL];
    __shared__ int wsum[8], wpre[8];

    const int b = blockIdx.x, t = threadIdx.x;
    const int lane = t & 63, w = t >> 6;
    h[t] = 0; cur[t] = 0;
    __syncthreads();

    const float* pb = pred + (size_t)b * NPTS * 3;
    int cid[8];
    #pragma unroll
    for (int k = 0; k < 8; ++k) {
        const int p = k * 512 + t;
        const float x = pb[3 * p], y = pb[3 * p + 1], z = pb[3 * p + 2];
        const int ix = min(GRIDD - 1, max(0, (int)(x * (float)GRIDD)));
        const int iy = min(GRIDD - 1, max(0, (int)(y * (float)GRIDD)));
        const int iz = min(GRIDD - 1, max(0, (int)(z * (float)GRIDD)));
        cid[k] = (ix << 6) | (iy << 3) | iz;
        atomicAdd(&h[cid[k]], 1);
    }
    __syncthreads();

    // Inclusive scan: per-wave shfl_up scan + 8-wave prefix.
    int v = h[t];
    #pragma unroll
    for (int off = 1; off < 64; off <<= 1) {
        const int u = __shfl_up(v, off, 64);
        if (lane >= off) v += u;
    }
    if (lane == 63) wsum[w] = v;
    __syncthreads();
    if (t < 8) {
        int s = 0;
        for (int i = 0; i < t; ++i) s += wsum[i];
        wpre[t] = s;
    }
    __syncthreads();
    start[t] = v + wpre[w] - h[t];               // exclusive start
    __syncthreads();

    #pragma unroll
    for (int k = 0; k < 8; ++k) {
        const int p = k * 512 + t;
        const float x = pb[3 * p], y = pb[3 * p + 1], z = pb[3 * p + 2];
        const int dst = start[cid[k]] + atomicAdd(&cur[cid[k]], 1);
        sortedP[(size_t)b * NPTS + dst] = make_float4(x, y, z, 0.0f);
    }

    cellStart[b * (NCELL + 1) + t] = start[t];
    if (t == 0) cellStart[b * (NCELL + 1) + NCELL] = NPTS;
}

// ---------------------------------------------------------------------------
// Kernel B: grid kNN search, 4 lanes per query. Each sublane r scans its
// stride-4 slice of the 9 contiguous z-ranges (disjoint sets), then exact
// union-top-6 via 2 shfl_xor merges. Coverage test L[5] <= COV2 proves
// global exactness; failures (~1-2%) brute-forced wave-cooperatively inline.
// ---------------------------------------------------------------------------
__global__ __launch_bounds__(THREADS) void search_kernel(
    const float4* __restrict__ sortedP, const int* __restrict__ cellStart,
    float* __restrict__ partial)
{
    __shared__ int cs[NCELL + 1];
    __shared__ float red[THREADS / 64];

    const int qidx = blockIdx.x * (THREADS / 4) + (threadIdx.x >> 2);
    const int r    = threadIdx.x & 3;            // sublane within query group
    const int b    = qidx >> 12;                 // batch (uniform per block)

    const int* cbase = cellStart + b * (NCELL + 1);
    for (int i = threadIdx.x; i < NCELL + 1; i += THREADS) cs[i] = cbase[i];
    __syncthreads();

    const float4 me = sortedP[qidx];
    const int ix = min(GRIDD - 1, max(0, (int)(me.x * (float)GRIDD)));
    const int iy = min(GRIDD - 1, max(0, (int)(me.y * (float)GRIDD)));
    const int iz = min(GRIDD - 1, max(0, (int)(me.z * (float)GRIDD)));

    float L[6];
    #pragma unroll
    for (int i = 0; i < 6; ++i) L[i] = 1e30f;

    const float4* sp = sortedP + (size_t)b * NPTS;
    const int z0 = max(iz - 1, 0), z1 = min(iz + 1, GRIDD - 1);

    #pragma unroll
    for (int dxy = 0; dxy < 9; ++dxy) {
        const int X = ix + (dxy / 3) - 1;
        const int Y = iy + (dxy % 3) - 1;
        if ((unsigned)X > (unsigned)(GRIDD - 1)) continue;
        if ((unsigned)Y > (unsigned)(GRIDD - 1)) continue;
        const int row = (X << 6) | (Y << 3);
        const int pe  = cs[row + z1 + 1];
        for (int p = cs[row + z0] + r; p < pe; p += 4) {
            const float4 c = sp[p];
            const float ddx = c.x - me.x;
            const float ddy = c.y - me.y;
            const float ddz = c.z - me.z;
            const float d = fmaf(ddz, ddz, fmaf(ddy, ddy, ddx * ddx));
            INS6(L, d);
        }
    }

    // Exact union-top-6 across the 4 disjoint sublane sets.
    #pragma unroll
    for (int m = 1; m <= 2; m <<= 1) {
        float R[6];
        #pragma unroll
        for (int i = 0; i < 6; ++i) R[i] = __shfl_xor(L[i], m, 64);
        #pragma unroll
        for (int i = 0; i < 6; ++i) INS6(L, R[i]);
    }

    const bool owner = (r == 0);
    const bool ok    = (L[5] <= COV2);
    float loss = (owner && ok) ? loss5(L) : 0.0f;

    // Wave-cooperative exact brute force for flagged queries (rare).
    const int lane = threadIdx.x & 63;
    unsigned long long flagged = __ballot(owner && !ok);
    while (flagged) {
        const int src = __ffsll(flagged) - 1;
        flagged &= flagged - 1;
        const float mx = __shfl(me.x, src, 64);
        const float my = __shfl(me.y, src, 64);
        const float mz = __shfl(me.z, src, 64);
        float F[6];
        #pragma unroll
        for (int i = 0; i < 6; ++i) F[i] = 1e30f;
        for (int p = lane; p < NPTS; p += 64) {
            const float4 c = sp[p];
            const float ddx = c.x - mx;
            const float ddy = c.y - my;
            const float ddz = c.z - mz;
            const float d = fmaf(ddz, ddz, fmaf(ddy, ddy, ddx * ddx));
            INS6(F, d);
        }
        #pragma unroll
        for (int off = 32; off >= 1; off >>= 1) {   // tree merge -> lane 0
            float R[6];
            #pragma unroll
            for (int i = 0; i < 6; ++i) R[i] = __shfl_down(F[i], off, 64);
            #pragma unroll
            for (int i = 0; i < 6; ++i) INS6(F, R[i]);
        }
        if (lane == 0) loss += loss5(F);
    }

    #pragma unroll
    for (int off = 32; off > 0; off >>= 1)
        loss += __shfl_down(loss, off, 64);
    const int wave = threadIdx.x >> 6;
    if (lane == 0) red[wave] = loss;
    __syncthreads();
    if (threadIdx.x == 0) {
        float ssum = 0.0f;
        #pragma unroll
        for (int w = 0; w < THREADS / 64; ++w) ssum += red[w];
        partial[blockIdx.x] = ssum;   // block = 64 consecutive queries
    }
}

// 1024 partials (64 per batch). 256 threads: t handles 4, 16-lane reduce.
__global__ void final_kernel(const float* __restrict__ partial,
                             float* __restrict__ out)
{
    const int t = threadIdx.x;
    const int bb = t >> 4, j = t & 15;
    float s = 0.0f;
    #pragma unroll
    for (int i = 0; i < 4; ++i) s += partial[bb * 64 + j * 4 + i];
    #pragma unroll
    for (int off = 8; off > 0; off >>= 1)
        s += __shfl_down(s, off, 16);
    if (j == 0) out[bb] = s * (1.0f / ((float)NPTS * 5.0f));
}

// ---------------------------------------------------------------------------
// Emergency path (tiny workspace): monolithic brute force.
// ---------------------------------------------------------------------------
__global__ __launch_bounds__(THREADS) void mono_kernel(
    const float* __restrict__ pred, float* __restrict__ partial)
{
    __shared__ __align__(16) float sx[NPTS];
    __shared__ __align__(16) float sy[NPTS];
    __shared__ __align__(16) float sz[NPTS];
    __shared__ float red[THREADS / 64];

    const int b     = blockIdx.x >> 4;
    const int chunk = blockIdx.x & 15;
    const float* pb = pred + (size_t)b * NPTS * 3;

    for (int p = threadIdx.x; p < NPTS; p += THREADS) {
        sx[p] = pb[3 * p + 0]; sy[p] = pb[3 * p + 1]; sz[p] = pb[3 * p + 2];
    }
    __syncthreads();

    const int n = chunk * THREADS + threadIdx.x;
    const float qx = pb[3 * n], qy = pb[3 * n + 1], qz = pb[3 * n + 2];

    float A[6], B[6];
    #pragma unroll
    for (int i = 0; i < 6; ++i) { A[i] = 1e30f; B[i] = 1e30f; }

    const float4* X4 = (const float4*)sx;
    const float4* Y4 = (const float4*)sy;
    const float4* Z4 = (const float4*)sz;

    #pragma unroll 2
    for (int g = 0; g < NPTS / 4; ++g) {
        const float4 X = X4[g], Y = Y4[g], Z = Z4[g];
        const float dx0 = X.x - qx, dy0 = Y.x - qy, dz0 = Z.x - qz;
        const float dx1 = X.y - qx, dy1 = Y.y - qy, dz1 = Z.y - qz;
        const float dx2 = X.z - qx, dy2 = Y.z - qy, dz2 = Z.z - qz;
        const float dx3 = X.w - qx, dy3 = Y.w - qy, dz3 = Z.w - qz;
        const float d0 = fmaf(dz0, dz0, fmaf(dy0, dy0, dx0 * dx0));
        const float d1 = fmaf(dz1, dz1, fmaf(dy1, dy1, dx1 * dx1));
        const float d2 = fmaf(dz2, dz2, fmaf(dy2, dy2, dx2 * dx2));
        const float d3 = fmaf(dz3, dz3, fmaf(dy3, dy3, dx3 * dx3));
        INS6(A, d0);
        INS6(B, d1);
        INS6(A, d2);
        INS6(B, d3);
    }
    #pragma unroll
    for (int i = 0; i < 6; ++i) INS6(A, B[i]);

    float loss = loss5(A);
    #pragma unroll
    for (int off = 32; off > 0; off >>= 1)
        loss += __shfl_down(loss, off, 64);
    const int wave = threadIdx.x >> 6, lane = threadIdx.x & 63;
    if (lane == 0) red[wave] = loss;
    __syncthreads();
    if (threadIdx.x == 0) {
        float s = 0.0f;
        #pragma unroll
        for (int w = 0; w < THREADS / 64; ++w) s += red[w];
        partial[blockIdx.x] = s;
    }
}

__global__ void mono_final_kernel(const float* __restrict__ partial,
                                  float* __restrict__ out)
{
    const int b = threadIdx.x;
    if (b < NB) {
        float s = 0.0f;
        #pragma unroll
        for (int i = 0; i < 16; ++i) s += partial[b * 16 + i];
        out[b] = s * (1.0f / ((float)NPTS * 5.0f));
    }
}

extern "C" void kernel_launch(void* const* d_in, const int* in_sizes, int n_in,
                              void* d_out, int out_size, void* d_ws, size_t ws_size,
                              hipStream_t stream)
{
    const float* pred = (const float*)d_in[0];
    float* out        = (float*)d_out;
    char* ws          = (char*)d_ws;

    const size_t off_sorted = 0;                               // 16*4096*16 B
    const size_t off_cs     = off_sorted + (size_t)NB * NPTS * sizeof(float4);
    const size_t off_part   = off_cs + (size_t)NB * (NCELL + 1) * sizeof(int);
    const size_t need       = off_part + 1024 * sizeof(float);

    if (ws_size >= need) {
        float4* sortedP = (float4*)(ws + off_sorted);
        int*    cellS   = (int*)(ws + off_cs);
        float*  partial = (float*)(ws + off_part);

        bin_kernel<<<dim3(NB), dim3(512), 0, stream>>>(pred, sortedP, cellS);
        search_kernel<<<dim3(NB * NPTS / (THREADS / 4)), dim3(THREADS), 0, stream>>>(
            sortedP, cellS, partial);
        final_kernel<<<dim3(1), dim3(256), 0, stream>>>(partial, out);
    } else {
        float* partial = (float*)d_ws;                 // 256 floats
        mono_kernel<<<dim3(256), dim3(THREADS), 0, stream>>>(pred, partial);
        mono_final_kernel<<<dim3(1), dim3(64), 0, stream>>>(partial, out);
    }
}

// Round 6
// 33.902 us; speedup vs baseline: 2.4172x; 1.7334x over previous
//
#include <hip/hip_runtime.h>
#include <math.h>

#define NPTS 4096
#define NB 16
#define THREADS 256
#define RADIUSF 0.07f
#define HF 0.03f
#define EPSF 1e-12f

#define GRIDD 8
#define NCELL (GRIDD * GRIDD * GRIDD)   // 512
#define HCELL 0.125f                    // cell edge

// Insert d into sorted-ascending 6-list: L0'=min(L0,d), Lk'=med3(d,L(k-1),Lk).
#define INS6(L, dd) do {                                          \
    const float _d  = (dd);                                       \
    const float _n0 = fminf((L)[0], _d);                          \
    const float _n1 = __builtin_amdgcn_fmed3f(_d, (L)[0], (L)[1]);\
    const float _n2 = __builtin_amdgcn_fmed3f(_d, (L)[1], (L)[2]);\
    const float _n3 = __builtin_amdgcn_fmed3f(_d, (L)[2], (L)[3]);\
    const float _n4 = __builtin_amdgcn_fmed3f(_d, (L)[3], (L)[4]);\
    const float _n5 = __builtin_amdgcn_fmed3f(_d, (L)[4], (L)[5]);\
    (L)[0]=_n0; (L)[1]=_n1; (L)[2]=_n2; (L)[3]=_n3; (L)[4]=_n4; (L)[5]=_n5; \
} while (0)

__device__ __forceinline__ float loss5(const float* L) {
    float loss = 0.0f;
    #pragma unroll
    for (int i = 1; i < 6; ++i) {               // L[0] == self (exact 0)
        const float d = sqrtf(fmaxf(L[i], EPSF));
        const float t = d / HF;
        loss += (RADIUSF - d) * expf(-t * t);
    }
    return loss;
}

// ---------------------------------------------------------------------------
// Kernel A: per batch, bin points into 8^3 cells (counting sort).
// ---------------------------------------------------------------------------
__global__ __launch_bounds__(512) void bin_kernel(
    const float* __restrict__ pred, float4* __restrict__ sortedP,
    int* __restrict__ cellStart)
{
    __shared__ int h[NCELL];
    __shared__ int cur[NCELL];
    __shared__ int start[NCELL];
    __shared__ int wsum[8], wpre[8];

    const int b = blockIdx.x, t = threadIdx.x;
    const int lane = t & 63, w = t >> 6;
    h[t] = 0; cur[t] = 0;
    __syncthreads();

    const float* pb = pred + (size_t)b * NPTS * 3;
    int cid[8];
    #pragma unroll
    for (int k = 0; k < 8; ++k) {
        const int p = k * 512 + t;
        const float x = pb[3 * p], y = pb[3 * p + 1], z = pb[3 * p + 2];
        const int ix = min(GRIDD - 1, max(0, (int)(x * (float)GRIDD)));
        const int iy = min(GRIDD - 1, max(0, (int)(y * (float)GRIDD)));
        const int iz = min(GRIDD - 1, max(0, (int)(z * (float)GRIDD)));
        cid[k] = (ix << 6) | (iy << 3) | iz;
        atomicAdd(&h[cid[k]], 1);
    }
    __syncthreads();

    int v = h[t];
    #pragma unroll
    for (int off = 1; off < 64; off <<= 1) {
        const int u = __shfl_up(v, off, 64);
        if (lane >= off) v += u;
    }
    if (lane == 63) wsum[w] = v;
    __syncthreads();
    if (t < 8) {
        int s = 0;
        for (int i = 0; i < t; ++i) s += wsum[i];
        wpre[t] = s;
    }
    __syncthreads();
    start[t] = v + wpre[w] - h[t];               // exclusive start
    __syncthreads();

    #pragma unroll
    for (int k = 0; k < 8; ++k) {
        const int p = k * 512 + t;
        const float x = pb[3 * p], y = pb[3 * p + 1], z = pb[3 * p + 2];
        const int dst = start[cid[k]] + atomicAdd(&cur[cid[k]], 1);
        sortedP[(size_t)b * NPTS + dst] = make_float4(x, y, z, 0.0f);
    }

    cellStart[b * (NCELL + 1) + t] = start[t];
    if (t == 0) cellStart[b * (NCELL + 1) + NCELL] = NPTS;
}

// ---------------------------------------------------------------------------
// Kernel B: grid kNN search, 8 lanes per query.
// Level 1: shifted-clamped 3^3 window, per-query coverage proof.
// Level 2 (rare, ~0.5%): wave-cooperative 5^3 window, coverage >= 2h.
// Level 3 (P~1e-11): wave-cooperative full brute force. All exact.
// ---------------------------------------------------------------------------
__global__ __launch_bounds__(THREADS) void search_kernel(
    const float4* __restrict__ sortedP, const int* __restrict__ cellStart,
    float* __restrict__ partial)
{
    __shared__ int cs[NCELL + 1];
    __shared__ float red[THREADS / 64];

    const int qidx = blockIdx.x * (THREADS / 8) + (threadIdx.x >> 3);
    const int r    = threadIdx.x & 7;            // sublane within query group
    const int b    = qidx >> 12;                 // batch (uniform per block)
    const int lane = threadIdx.x & 63;

    const int* cbase = cellStart + b * (NCELL + 1);
    for (int i = threadIdx.x; i < NCELL + 1; i += THREADS) cs[i] = cbase[i];
    __syncthreads();

    const float4 me = sortedP[qidx];
    const int ix = min(GRIDD - 1, max(0, (int)(me.x * (float)GRIDD)));
    const int iy = min(GRIDD - 1, max(0, (int)(me.y * (float)GRIDD)));
    const int iz = min(GRIDD - 1, max(0, (int)(me.z * (float)GRIDD)));
    const int X0 = min(max(ix - 1, 0), GRIDD - 3);   // shifted-clamped 3-window
    const int Y0 = min(max(iy - 1, 0), GRIDD - 3);
    const int Z0 = min(max(iz - 1, 0), GRIDD - 3);

    float L[6];
    #pragma unroll
    for (int i = 0; i < 6; ++i) L[i] = 1e30f;

    const float4* sp = sortedP + (size_t)b * NPTS;

    #pragma unroll
    for (int c = 0; c < 9; ++c) {
        const int X = X0 + c / 3, Y = Y0 + c % 3;
        const int row = (X << 6) | (Y << 3);
        const int pe  = cs[row + Z0 + 3];
        for (int p = cs[row + Z0] + r; p < pe; p += 8) {
            const float4 cd = sp[p];
            const float ddx = cd.x - me.x;
            const float ddy = cd.y - me.y;
            const float ddz = cd.z - me.z;
            const float d = fmaf(ddz, ddz, fmaf(ddy, ddy, ddx * ddx));
            INS6(L, d);
        }
    }

    // Exact union-top-6 across the 8 disjoint sublane sets (butterfly).
    #pragma unroll
    for (int m = 1; m <= 4; m <<= 1) {
        float R[6];
        #pragma unroll
        for (int i = 0; i < 6; ++i) R[i] = __shfl_xor(L[i], m, 64);
        #pragma unroll
        for (int i = 0; i < 6; ++i) INS6(L, R[i]);
    }

    // Per-query coverage radius: distance from q to nearest NON-clamped
    // window face (clamped side = domain boundary = empty beyond = INF).
    float cov = 1e30f;
    if (X0 != 0)         cov = fminf(cov, me.x - (float)X0 * HCELL);
    if (X0 != GRIDD - 3) cov = fminf(cov, (float)(X0 + 3) * HCELL - me.x);
    if (Y0 != 0)         cov = fminf(cov, me.y - (float)Y0 * HCELL);
    if (Y0 != GRIDD - 3) cov = fminf(cov, (float)(Y0 + 3) * HCELL - me.y);
    if (Z0 != 0)         cov = fminf(cov, me.z - (float)Z0 * HCELL);
    if (Z0 != GRIDD - 3) cov = fminf(cov, (float)(Z0 + 3) * HCELL - me.z);

    const bool owner = (r == 0);
    const bool ok    = (L[5] <= cov * cov);
    float loss = (owner && ok) ? loss5(L) : 0.0f;

    // ---- Level 2: 5^3 window scan for flagged queries (wave-cooperative).
    unsigned long long flagged = __ballot(owner && !ok);
    while (flagged) {
        const int src = __ffsll((unsigned long long)flagged) - 1;
        flagged &= flagged - 1;
        const float mx = __shfl(me.x, src, 64);
        const float my = __shfl(me.y, src, 64);
        const float mz = __shfl(me.z, src, 64);
        const int jx = min(GRIDD - 1, max(0, (int)(mx * (float)GRIDD)));
        const int jy = min(GRIDD - 1, max(0, (int)(my * (float)GRIDD)));
        const int jz = min(GRIDD - 1, max(0, (int)(mz * (float)GRIDD)));
        const int eX0 = min(max(jx - 2, 0), GRIDD - 5);
        const int eY0 = min(max(jy - 2, 0), GRIDD - 5);
        const int eZ0 = min(max(jz - 2, 0), GRIDD - 5);

        float F[6];
        #pragma unroll
        for (int i = 0; i < 6; ++i) F[i] = 1e30f;

        const int col = lane >> 1, jj = lane & 1;    // 2 lanes per x-y column
        if (col < 25) {
            const int X = eX0 + col / 5, Y = eY0 + col % 5;
            const int row = (X << 6) | (Y << 3);
            const int pe  = cs[row + eZ0 + 5];
            for (int p = cs[row + eZ0] + jj; p < pe; p += 2) {
                const float4 cd = sp[p];
                const float ddx = cd.x - mx;
                const float ddy = cd.y - my;
                const float ddz = cd.z - mz;
                const float d = fmaf(ddz, ddz, fmaf(ddy, ddy, ddx * ddx));
                INS6(F, d);
            }
        }
        #pragma unroll
        for (int off = 32; off >= 1; off >>= 1) {    // tree merge -> lane 0
            float R[6];
            #pragma unroll
            for (int i = 0; i < 6; ++i) R[i] = __shfl_down(F[i], off, 64);
            #pragma unroll
            for (int i = 0; i < 6; ++i) INS6(F, R[i]);
        }

        float ecov = 1e30f;
        if (eX0 != 0)         ecov = fminf(ecov, mx - (float)eX0 * HCELL);
        if (eX0 != GRIDD - 5) ecov = fminf(ecov, (float)(eX0 + 5) * HCELL - mx);
        if (eY0 != 0)         ecov = fminf(ecov, my - (float)eY0 * HCELL);
        if (eY0 != GRIDD - 5) ecov = fminf(ecov, (float)(eY0 + 5) * HCELL - my);
        if (eZ0 != 0)         ecov = fminf(ecov, mz - (float)eZ0 * HCELL);
        if (eZ0 != GRIDD - 5) ecov = fminf(ecov, (float)(eZ0 + 5) * HCELL - mz);

        const int eok = __shfl((F[5] <= ecov * ecov) ? 1 : 0, 0, 64);
        if (eok) {
            if (lane == 0) loss += loss5(F);
        } else {
            // ---- Level 3: exact full brute force (effectively never).
            float G[6];
            #pragma unroll
            for (int i = 0; i < 6; ++i) G[i] = 1e30f;
            for (int p = lane; p < NPTS; p += 64) {
                const float4 cd = sp[p];
                const float ddx = cd.x - mx;
                const float ddy = cd.y - my;
                const float ddz = cd.z - mz;
                const float d = fmaf(ddz, ddz, fmaf(ddy, ddy, ddx * ddx));
                INS6(G, d);
            }
            #pragma unroll
            for (int off = 32; off >= 1; off >>= 1) {
                float R[6];
                #pragma unroll
                for (int i = 0; i < 6; ++i) R[i] = __shfl_down(G[i], off, 64);
                #pragma unroll
                for (int i = 0; i < 6; ++i) INS6(G, R[i]);
            }
            if (lane == 0) loss += loss5(G);
        }
    }

    #pragma unroll
    for (int off = 32; off > 0; off >>= 1)
        loss += __shfl_down(loss, off, 64);
    const int wave = threadIdx.x >> 6;
    if (lane == 0) red[wave] = loss;
    __syncthreads();
    if (threadIdx.x == 0) {
        float ssum = 0.0f;
        #pragma unroll
        for (int w = 0; w < THREADS / 64; ++w) ssum += red[w];
        partial[blockIdx.x] = ssum;   // block = 32 consecutive queries
    }
}

// 2048 partials (128 per batch). thread t: batch t>>4, 8 partials, 16-lane reduce.
__global__ void final_kernel(const float* __restrict__ partial,
                             float* __restrict__ out)
{
    const int t = threadIdx.x;
    const int bb = t >> 4, j = t & 15;
    float s = 0.0f;
    #pragma unroll
    for (int i = 0; i < 8; ++i) s += partial[bb * 128 + j * 8 + i];
    #pragma unroll
    for (int off = 8; off > 0; off >>= 1)
        s += __shfl_down(s, off, 16);
    if (j == 0) out[bb] = s * (1.0f / ((float)NPTS * 5.0f));
}

// ---------------------------------------------------------------------------
// Emergency path (tiny workspace): monolithic brute force.
// ---------------------------------------------------------------------------
__global__ __launch_bounds__(THREADS) void mono_kernel(
    const float* __restrict__ pred, float* __restrict__ partial)
{
    __shared__ __align__(16) float sx[NPTS];
    __shared__ __align__(16) float sy[NPTS];
    __shared__ __align__(16) float sz[NPTS];
    __shared__ float red[THREADS / 64];

    const int b     = blockIdx.x >> 4;
    const int chunk = blockIdx.x & 15;
    const float* pb = pred + (size_t)b * NPTS * 3;

    for (int p = threadIdx.x; p < NPTS; p += THREADS) {
        sx[p] = pb[3 * p + 0]; sy[p] = pb[3 * p + 1]; sz[p] = pb[3 * p + 2];
    }
    __syncthreads();

    const int n = chunk * THREADS + threadIdx.x;
    const float qx = pb[3 * n], qy = pb[3 * n + 1], qz = pb[3 * n + 2];

    float A[6], B[6];
    #pragma unroll
    for (int i = 0; i < 6; ++i) { A[i] = 1e30f; B[i] = 1e30f; }

    const float4* X4 = (const float4*)sx;
    const float4* Y4 = (const float4*)sy;
    const float4* Z4 = (const float4*)sz;

    #pragma unroll 2
    for (int g = 0; g < NPTS / 4; ++g) {
        const float4 X = X4[g], Y = Y4[g], Z = Z4[g];
        const float dx0 = X.x - qx, dy0 = Y.x - qy, dz0 = Z.x - qz;
        const float dx1 = X.y - qx, dy1 = Y.y - qy, dz1 = Z.y - qz;
        const float dx2 = X.z - qx, dy2 = Y.z - qy, dz2 = Z.z - qz;
        const float dx3 = X.w - qx, dy3 = Y.w - qy, dz3 = Z.w - qz;
        const float d0 = fmaf(dz0, dz0, fmaf(dy0, dy0, dx0 * dx0));
        const float d1 = fmaf(dz1, dz1, fmaf(dy1, dy1, dx1 * dx1));
        const float d2 = fmaf(dz2, dz2, fmaf(dy2, dy2, dx2 * dx2));
        const float d3 = fmaf(dz3, dz3, fmaf(dy3, dy3, dx3 * dx3));
        INS6(A, d0);
        INS6(B, d1);
        INS6(A, d2);
        INS6(B, d3);
    }
    #pragma unroll
    for (int i = 0; i < 6; ++i) INS6(A, B[i]);

    float loss = loss5(A);
    #pragma unroll
    for (int off = 32; off > 0; off >>= 1)
        loss += __shfl_down(loss, off, 64);
    const int wave = threadIdx.x >> 6, lane = threadIdx.x & 63;
    if (lane == 0) red[wave] = loss;
    __syncthreads();
    if (threadIdx.x == 0) {
        float s = 0.0f;
        #pragma unroll
        for (int w = 0; w < THREADS / 64; ++w) s += red[w];
        partial[blockIdx.x] = s;
    }
}

__global__ void mono_final_kernel(const float* __restrict__ partial,
                                  float* __restrict__ out)
{
    const int b = threadIdx.x;
    if (b < NB) {
        float s = 0.0f;
        #pragma unroll
        for (int i = 0; i < 16; ++i) s += partial[b * 16 + i];
        out[b] = s * (1.0f / ((float)NPTS * 5.0f));
    }
}

extern "C" void kernel_launch(void* const* d_in, const int* in_sizes, int n_in,
                              void* d_out, int out_size, void* d_ws, size_t ws_size,
                              hipStream_t stream)
{
    const float* pred = (const float*)d_in[0];
    float* out        = (float*)d_out;
    char* ws          = (char*)d_ws;

    const size_t off_sorted = 0;                               // 16*4096*16 B
    const size_t off_cs     = off_sorted + (size_t)NB * NPTS * sizeof(float4);
    const size_t off_part   = off_cs + (size_t)NB * (NCELL + 1) * sizeof(int);
    const size_t need       = off_part + 2048 * sizeof(float);

    if (ws_size >= need) {
        float4* sortedP = (float4*)(ws + off_sorted);
        int*    cellS   = (int*)(ws + off_cs);
        float*  partial = (float*)(ws + off_part);

        bin_kernel<<<dim3(NB), dim3(512), 0, stream>>>(pred, sortedP, cellS);
        search_kernel<<<dim3(NB * NPTS / (THREADS / 8)), dim3(THREADS), 0, stream>>>(
            sortedP, cellS, partial);
        final_kernel<<<dim3(1), dim3(256), 0, stream>>>(partial, out);
    } else {
        float* partial = (float*)d_ws;                 // 256 floats
        mono_kernel<<<dim3(256), dim3(THREADS), 0, stream>>>(pred, partial);
        mono_final_kernel<<<dim3(1), dim3(64), 0, stream>>>(partial, out);
    }
}